// Round 8
// baseline (1407.125 us; speedup 1.0000x reference)
//
#include <hip/hip_runtime.h>

// ParametrisedPooling: out[t] = sum_k w[n,k] * x_in[idx[n,k], :], n = indices_target[t]
//
// R8: two-phase L3-chunked gather. Traffic plan verified 3x (FETCH ~260 MB =
// unique-row floor). R7 was latency-bound: every gather sat in a divergent
// branch -> load+waitcnt+fma per basic block -> 1 outstanding load/wave.
// Fix: PARTITION each row's neighbors by phase in the prologue into two LDS
// lists PADDED to 7 with (idx=0, w=0). Phase body is branch-free: stage 7
// (s,w), issue 7 independent 512B gathers, then FMA. Dummy gathers hit row 0
// (L1-resident broadcast) with w=0. 7 KB in flight per wave -> BW-bound again.

constexpr int N_SRC = 655362;
constexpr int N6    = 163830;
constexpr int N7    = 12;
constexpr int N_OUT = N6 + N7;            // 163842
constexpr int D     = 128;
constexpr int CHUNK = N_SRC / 2 + 1;      // 327682: halves ~167.8 MB each

constexpr int BLOCK = 256;
constexpr int GRID  = 1024;               // 4 blocks/CU x 256 CU, co-resident
constexpr int GPB   = BLOCK / 32;         // 8 groups (32 lanes) per block
constexpr int NG    = GRID * GPB;         // 8192 groups
constexpr int ROWS  = (N_OUT + NG - 1) / NG;   // 21 (row = g + r*NG)
constexpr int B0    = 11;                 // batch A rows
constexpr int B1    = ROWS - B0;          // 10

struct Smem {
    int   idx[2][ROWS][GPB][8];           // [phase][row][group][slot]
    float w  [2][ROWS][GPB][8];
};

__device__ __forceinline__ void adv_barrier(unsigned int* cnt, unsigned target) {
    __syncthreads();
    if (cnt != nullptr) {
        if (threadIdx.x == 0) {
            __hip_atomic_fetch_add(cnt, 1u, __ATOMIC_ACQ_REL,
                                   __HIP_MEMORY_SCOPE_AGENT);
            int spins = 0;
            while (__hip_atomic_load(cnt, __ATOMIC_ACQUIRE,
                                     __HIP_MEMORY_SCOPE_AGENT) < target
                   && spins < 20000) {
                __builtin_amdgcn_s_sleep(2);
                ++spins;
            }
        }
        __syncthreads();
    }
}

template <int R0, int RN, int PHASE>
__device__ __forceinline__ void seg(float4* __restrict__ acc,
                                    const Smem& sm, int gl, int lane,
                                    const float* __restrict__ x_in) {
#pragma unroll
    for (int r = R0; r < R0 + RN; ++r) {
        int   s [7];
        float wv[7];
#pragma unroll
        for (int k = 0; k < 7; ++k) {
            s [k] = sm.idx[PHASE][r][gl][k];   // broadcast LDS reads
            wv[k] = sm.w  [PHASE][r][gl][k];
        }
        float4 v[7];
#pragma unroll
        for (int k = 0; k < 7; ++k)            // 7 independent gathers in flight
            v[k] = *reinterpret_cast<const float4*>(
                x_in + (size_t)s[k] * D + lane * 4);
#pragma unroll
        for (int k = 0; k < 7; ++k) {
            acc[r - R0].x += wv[k] * v[k].x;
            acc[r - R0].y += wv[k] * v[k].y;
            acc[r - R0].z += wv[k] * v[k].z;
            acc[r - R0].w += wv[k] * v[k].w;
        }
    }
}

template <int R0, int RN>
__device__ __forceinline__ void store_rows(const float4* __restrict__ acc,
                                           int g, int lane,
                                           float* __restrict__ out) {
#pragma unroll
    for (int r = R0; r < R0 + RN; ++r) {
        const int row = g + r * NG;
        if (row < N_OUT) {
            float* op = out + (size_t)row * D + lane * 4;
            __builtin_nontemporal_store(acc[r - R0].x, op + 0);
            __builtin_nontemporal_store(acc[r - R0].y, op + 1);
            __builtin_nontemporal_store(acc[r - R0].z, op + 2);
            __builtin_nontemporal_store(acc[r - R0].w, op + 3);
        }
    }
}

__global__ __launch_bounds__(BLOCK, 4) void pool_kernel(
    const float* __restrict__ x_in,
    const float* __restrict__ w6,
    const float* __restrict__ w7,
    const int*   __restrict__ idx6,
    const int*   __restrict__ idx7,
    const int*   __restrict__ tgt,
    float*       __restrict__ out,
    unsigned int* barrier_cnt)
{
    __shared__ Smem sm;

    // ---- prologue: partition each row's neighbors by phase, pad to 7 ----
    for (int e = threadIdx.x; e < ROWS * GPB; e += BLOCK) {
        const int r   = e / GPB;
        const int gl  = e % GPB;
        const int row = (blockIdx.x * GPB + gl) + r * NG;
        int c0 = 0, c1 = 0;
        if (row < N_OUT) {
            const int n = tgt[row];
            const bool six = (n < N6);
            const int deg  = six ? 6 : 7;
            const int*   ip = six ? idx6 + 6 * (size_t)n
                                  : idx7 + 7 * (size_t)(n - N6);
            const float* wp = six ? w6 + 6 * (size_t)n
                                  : w7 + 7 * (size_t)(n - N6);
            for (int k = 0; k < deg; ++k) {
                const int   sv = ip[k];
                const float wv = wp[k];
                if (sv < CHUNK) {
                    sm.idx[0][r][gl][c0] = sv; sm.w[0][r][gl][c0] = wv; ++c0;
                } else {
                    sm.idx[1][r][gl][c1] = sv; sm.w[1][r][gl][c1] = wv; ++c1;
                }
            }
        }
        for (int k = c0; k < 7; ++k) { sm.idx[0][r][gl][k] = 0; sm.w[0][r][gl][k] = 0.f; }
        for (int k = c1; k < 7; ++k) { sm.idx[1][r][gl][k] = 0; sm.w[1][r][gl][k] = 0.f; }
    }
    __syncthreads();

    const int gl   = threadIdx.x >> 5;
    const int lane = threadIdx.x & 31;
    const int g    = blockIdx.x * GPB + gl;

    float4 acc[B0];

    // ---- batch A (rows 0..10) ----
#pragma unroll
    for (int i = 0; i < B0; ++i) acc[i] = make_float4(0.f, 0.f, 0.f, 0.f);
    seg<0, B0, 0>(acc, sm, gl, lane, x_in);          // lower half of x_in
    adv_barrier(barrier_cnt, 1u * GRID);
    seg<0, B0, 1>(acc, sm, gl, lane, x_in);          // upper half
    store_rows<0, B0>(acc, g, lane, out);
    adv_barrier(barrier_cnt, 2u * GRID);

    // ---- batch B (rows 11..20) ----
#pragma unroll
    for (int i = 0; i < B1; ++i) acc[i] = make_float4(0.f, 0.f, 0.f, 0.f);
    seg<B0, B1, 0>(acc, sm, gl, lane, x_in);         // lower half
    adv_barrier(barrier_cnt, 3u * GRID);
    seg<B0, B1, 1>(acc, sm, gl, lane, x_in);         // upper half
    store_rows<B0, B1>(acc, g, lane, out);
}

extern "C" void kernel_launch(void* const* d_in, const int* in_sizes, int n_in,
                              void* d_out, int out_size, void* d_ws, size_t ws_size,
                              hipStream_t stream) {
    const float* x_in = (const float*)d_in[0];
    const float* w6   = (const float*)d_in[1];
    const float* w7   = (const float*)d_in[2];
    const int*   idx6 = (const int*)d_in[3];
    const int*   idx7 = (const int*)d_in[4];
    const int*   tgt  = (const int*)d_in[5];
    float*       out  = (float*)d_out;

    unsigned int* barrier_cnt = nullptr;
    if (ws_size >= sizeof(unsigned int)) {
        barrier_cnt = (unsigned int*)d_ws;
        hipMemsetAsync(barrier_cnt, 0, sizeof(unsigned int), stream);
    }

    pool_kernel<<<GRID, BLOCK, 0, stream>>>(x_in, w6, w7, idx6, idx7, tgt,
                                            out, barrier_cnt);
}

// Round 9
// 109.696 us; speedup vs baseline: 12.8275x; 12.8275x over previous
//
#include <hip/hip_runtime.h>

// ParametrisedPooling: out[t] = sum_k w[n,k] * x_in[idx[n,k], :], n = indices_target[t]
//
// R9: two-LAUNCH L3-chunked gather (no persistence, no barriers, no spill
// surface). Traffic theory verified 3x (phased FETCH = unique-row floor
// ~260 MB); register-persistent execution failed 3x (spill/serialization).
// So: phase across two stream-ordered launches of the PROVEN R3 structure
// (one 32-lane group per output row, 6-7 independent 512B gathers in flight):
//   K1: accumulate neighbors with s <  CHUNK -> bf16 partials in d_ws
//       (42 MB, plain cached stores -> stays L3-resident for K2).
//   K2: accumulate neighbors with s >= CHUNK + partial -> f32 out (nt store).
// Phase filter is branch-free (cndmask): s_eff = c ? s : 0, w_eff = c ? w : 0;
// dummy gathers hit L1-resident row 0 and contribute 0.
// Fallback: single unphased kernel if ws_size < partial buffer.

constexpr int N_SRC = 655362;
constexpr int N6    = 163830;
constexpr int N7    = 12;
constexpr int N_OUT = N6 + N7;            // 163842
constexpr int D     = 128;
constexpr int CHUNK = N_SRC / 2 + 1;      // 327682: halves ~167.8 MB each

constexpr int BLOCK = 256;
constexpr int GPB   = BLOCK / 32;         // 8 rows (32-lane groups) per block
constexpr int GRID_ROWS = (N_OUT + GPB - 1) / GPB;   // 20481

__device__ __forceinline__ unsigned short f2bf(float f) {
    unsigned u = __builtin_bit_cast(unsigned, f);
    unsigned r = (u + 0x7FFFu + ((u >> 16) & 1u)) >> 16;   // RNE
    return (unsigned short)r;
}
__device__ __forceinline__ float bf2f(unsigned short h) {
    unsigned u = ((unsigned)h) << 16;
    return __builtin_bit_cast(float, u);
}

template <int PHASE, int DEG>
__device__ __forceinline__ float4 gather_row(const float* __restrict__ x_in,
                                             const int* __restrict__ ip,
                                             const float* __restrict__ wp,
                                             int lane) {
    int   se[DEG];
    float we[DEG];
#pragma unroll
    for (int k = 0; k < DEG; ++k) {
        const int   s = ip[k];
        const float w = wp[k];
        const bool  c = (PHASE == 0) ? (s < CHUNK) : (s >= CHUNK);
        se[k] = c ? s : 0;        // dummy -> row 0 (L1-resident broadcast)
        we[k] = c ? w : 0.f;      // dummy contributes 0
    }
    float4 v[DEG];
#pragma unroll
    for (int k = 0; k < DEG; ++k)     // DEG independent gathers in flight
        v[k] = *reinterpret_cast<const float4*>(
            x_in + (size_t)se[k] * D + lane * 4);
    float4 a = make_float4(0.f, 0.f, 0.f, 0.f);
#pragma unroll
    for (int k = 0; k < DEG; ++k) {
        a.x += we[k] * v[k].x;
        a.y += we[k] * v[k].y;
        a.z += we[k] * v[k].z;
        a.w += we[k] * v[k].w;
    }
    return a;
}

template <int PHASE>
__global__ __launch_bounds__(BLOCK) void pool_phase_kernel(
    const float* __restrict__ x_in,
    const float* __restrict__ w6,
    const float* __restrict__ w7,
    const int*   __restrict__ idx6,
    const int*   __restrict__ idx7,
    const int*   __restrict__ tgt,
    unsigned short* __restrict__ part,   // [N_OUT][D] bf16 partials (d_ws)
    float*       __restrict__ out)
{
    const int row  = blockIdx.x * GPB + (threadIdx.x >> 5);
    const int lane = threadIdx.x & 31;
    if (row >= N_OUT) return;

    const int n = tgt[row];

    // K2: issue the partial read early so it overlaps the gathers.
    ushort4 pin;
    if (PHASE == 1)
        pin = *reinterpret_cast<const ushort4*>(part + (size_t)row * D + lane * 4);

    float4 acc;
    if (n < N6) {
        acc = gather_row<PHASE, 6>(x_in, idx6 + 6 * (size_t)n,
                                   w6 + 6 * (size_t)n, lane);
    } else {
        const int m = n - N6;
        acc = gather_row<PHASE, 7>(x_in, idx7 + 7 * (size_t)m,
                                   w7 + 7 * (size_t)m, lane);
    }

    if (PHASE == 0) {
        // bf16 partial, PLAIN store (allocate in cache; K2 re-reads it)
        ushort4 p;
        p.x = f2bf(acc.x); p.y = f2bf(acc.y);
        p.z = f2bf(acc.z); p.w = f2bf(acc.w);
        *reinterpret_cast<ushort4*>(part + (size_t)row * D + lane * 4) = p;
    } else {
        acc.x += bf2f(pin.x);
        acc.y += bf2f(pin.y);
        acc.z += bf2f(pin.z);
        acc.w += bf2f(pin.w);
        float* op = out + (size_t)row * D + lane * 4;
        __builtin_nontemporal_store(acc.x, op + 0);
        __builtin_nontemporal_store(acc.y, op + 1);
        __builtin_nontemporal_store(acc.z, op + 2);
        __builtin_nontemporal_store(acc.w, op + 3);
    }
}

// Fallback: R3's proven single-pass kernel (92.3 us) if d_ws is too small.
__global__ __launch_bounds__(BLOCK) void pool_simple_kernel(
    const float* __restrict__ x_in,
    const float* __restrict__ w6,
    const float* __restrict__ w7,
    const int*   __restrict__ idx6,
    const int*   __restrict__ idx7,
    const int*   __restrict__ tgt,
    float*       __restrict__ out)
{
    const int row  = blockIdx.x * GPB + (threadIdx.x >> 5);
    const int lane = threadIdx.x & 31;
    if (row >= N_OUT) return;
    const int n = tgt[row];
    float4 acc = make_float4(0.f, 0.f, 0.f, 0.f);
    if (n < N6) {
        const int*   ip = idx6 + 6 * (size_t)n;
        const float* wp = w6   + 6 * (size_t)n;
#pragma unroll
        for (int k = 0; k < 6; ++k) {
            const float w  = wp[k];
            const float4 v = *reinterpret_cast<const float4*>(
                x_in + (size_t)ip[k] * D + lane * 4);
            acc.x += w * v.x; acc.y += w * v.y;
            acc.z += w * v.z; acc.w += w * v.w;
        }
    } else {
        const int m = n - N6;
        const int*   ip = idx7 + 7 * (size_t)m;
        const float* wp = w7   + 7 * (size_t)m;
#pragma unroll
        for (int k = 0; k < 7; ++k) {
            const float w  = wp[k];
            const float4 v = *reinterpret_cast<const float4*>(
                x_in + (size_t)ip[k] * D + lane * 4);
            acc.x += w * v.x; acc.y += w * v.y;
            acc.z += w * v.z; acc.w += w * v.w;
        }
    }
    float* op = out + (size_t)row * D + lane * 4;
    __builtin_nontemporal_store(acc.x, op + 0);
    __builtin_nontemporal_store(acc.y, op + 1);
    __builtin_nontemporal_store(acc.z, op + 2);
    __builtin_nontemporal_store(acc.w, op + 3);
}

extern "C" void kernel_launch(void* const* d_in, const int* in_sizes, int n_in,
                              void* d_out, int out_size, void* d_ws, size_t ws_size,
                              hipStream_t stream) {
    const float* x_in = (const float*)d_in[0];
    const float* w6   = (const float*)d_in[1];
    const float* w7   = (const float*)d_in[2];
    const int*   idx6 = (const int*)d_in[3];
    const int*   idx7 = (const int*)d_in[4];
    const int*   tgt  = (const int*)d_in[5];
    float*       out  = (float*)d_out;

    const size_t part_bytes = (size_t)N_OUT * D * sizeof(unsigned short); // 41.9 MB
    if (ws_size >= part_bytes) {
        unsigned short* part = (unsigned short*)d_ws;
        pool_phase_kernel<0><<<GRID_ROWS, BLOCK, 0, stream>>>(
            x_in, w6, w7, idx6, idx7, tgt, part, out);
        pool_phase_kernel<1><<<GRID_ROWS, BLOCK, 0, stream>>>(
            x_in, w6, w7, idx6, idx7, tgt, part, out);
    } else {
        pool_simple_kernel<<<GRID_ROWS, BLOCK, 0, stream>>>(
            x_in, w6, w7, idx6, idx7, tgt, out);
    }
}

// Round 10
// 92.945 us; speedup vs baseline: 15.1394x; 1.1802x over previous
//
#include <hip/hip_runtime.h>

// ParametrisedPooling: out[t] = sum_k w[n,k] * x_in[idx[n,k], :], n = indices_target[t]
// N6 = 163830 coarse nodes with 6 neighbors, N7 = 12 with 7 neighbors, D = 128.
//
// FINAL (revert to R3, the best measured realization: 92.3 us, absmax 0).
// Nine-round conclusion: the op is bound by random-access DRAM efficiency
// (~4.5 TB/s on 983k x 512 B uniform-random row fetches), not by bytes.
// - Byte floor 358 MB verified via phased variants (FETCH 260-292 MB), but
//   every phased realization ran at <= 4 TB/s effective and lost (best 109.7).
// - This kernel: ~416 MB at 4.5 TB/s effective = ~92 us ~= measured. Roofline.
// Structure: one 32-lane group per output row, 6-7 independent 512 B gathers
// in flight, wave-uniform idx/weight broadcasts, nt store on the write-once out.

constexpr int N6     = 163830;
constexpr int N7     = 12;
constexpr int N_OUT  = N6 + N7;   // 163842
constexpr int D      = 128;
constexpr int LANES_PER_ROW = 32;          // 32 lanes x float4 = 128 floats
constexpr int BLOCK  = 256;
constexpr int ROWS_PER_BLOCK = BLOCK / LANES_PER_ROW;  // 8

__global__ __launch_bounds__(BLOCK) void pooling_kernel(
    const float* __restrict__ x_in,      // [N_SRC, D]
    const float* __restrict__ w6,        // [N6, 6]
    const float* __restrict__ w7,        // [N7, 7]
    const int*   __restrict__ idx6,      // [N6, 6]
    const int*   __restrict__ idx7,      // [N7, 7]
    const int*   __restrict__ tgt,       // [N_OUT]
    float*       __restrict__ out)       // [N_OUT, D]
{
    const int row  = blockIdx.x * ROWS_PER_BLOCK + (threadIdx.x >> 5);
    const int lane = threadIdx.x & 31;
    if (row >= N_OUT) return;

    const int n = tgt[row];

    float4 acc = make_float4(0.f, 0.f, 0.f, 0.f);

    if (n < N6) {
        const int*   ip = idx6 + (size_t)n * 6;
        const float* wp = w6   + (size_t)n * 6;
#pragma unroll
        for (int k = 0; k < 6; ++k) {
            const int   src = ip[k];
            const float w   = wp[k];
            const float4 v  = *reinterpret_cast<const float4*>(
                x_in + (size_t)src * D + (size_t)lane * 4);
            acc.x += w * v.x;
            acc.y += w * v.y;
            acc.z += w * v.z;
            acc.w += w * v.w;
        }
    } else {
        const int m = n - N6;
        const int*   ip = idx7 + (size_t)m * 7;
        const float* wp = w7   + (size_t)m * 7;
#pragma unroll
        for (int k = 0; k < 7; ++k) {
            const int   src = ip[k];
            const float w   = wp[k];
            const float4 v  = *reinterpret_cast<const float4*>(
                x_in + (size_t)src * D + (size_t)lane * 4);
            acc.x += w * v.x;
            acc.y += w * v.y;
            acc.z += w * v.z;
            acc.w += w * v.w;
        }
    }

    float* op = out + (size_t)row * D + (size_t)lane * 4;
    __builtin_nontemporal_store(acc.x, op + 0);
    __builtin_nontemporal_store(acc.y, op + 1);
    __builtin_nontemporal_store(acc.z, op + 2);
    __builtin_nontemporal_store(acc.w, op + 3);
}

extern "C" void kernel_launch(void* const* d_in, const int* in_sizes, int n_in,
                              void* d_out, int out_size, void* d_ws, size_t ws_size,
                              hipStream_t stream) {
    const float* x_in = (const float*)d_in[0];
    const float* w6   = (const float*)d_in[1];
    const float* w7   = (const float*)d_in[2];
    const int*   idx6 = (const int*)d_in[3];
    const int*   idx7 = (const int*)d_in[4];
    const int*   tgt  = (const int*)d_in[5];
    float*       out  = (float*)d_out;

    const int grid = (N_OUT + ROWS_PER_BLOCK - 1) / ROWS_PER_BLOCK;
    pooling_kernel<<<grid, BLOCK, 0, stream>>>(x_in, w6, w7, idx6, idx7, tgt, out);
}